// Round 7
// baseline (1136.481 us; speedup 1.0000x reference)
//
#include <hip/hip_runtime.h>

#define IN_C 300
#define OUT_C 200
#define NEG_SLOPE 0.2f

// W-stationary GEMM geometry
#define BMB 64   // rows per block (4 waves x 16)
#define BMW 16   // rows per wave
#define BKC 20   // K chunk (divides 300 and 200)
#define WF4 1000 // float4 slots per W chunk = 20*200/4

static inline int cdiv(long a, int b) { return (int)((a + b - 1) / b); }

// broadcast lane value to SGPR via v_readlane (VALU pipe, NOT the LDS pipe)
__device__ __forceinline__ float rdlane(float v, int l) {
  return __int_as_float(__builtin_amdgcn_readlane(__float_as_int(v), l));
}

// ---------------- utility ----------------
__global__ __launch_bounds__(256)
void zero_int_kernel(int* __restrict__ p, int n) {
  int i = blockIdx.x * blockDim.x + threadIdx.x;
  if (i < n) p[i] = 0;
}

__device__ __forceinline__ void edge_sd(const int* __restrict__ src,
                                        const int* __restrict__ dst,
                                        int i, int E, int& s, int& d) {
  if (i < E) { s = src[i]; d = dst[i]; } else { s = d = i - E; }
}

// ---------------- CSR build ----------------
__global__ __launch_bounds__(256)
void hist_kernel(const int* __restrict__ src, const int* __restrict__ dst,
                 int E, int ET, int* __restrict__ counts) {
  int i = blockIdx.x * blockDim.x + threadIdx.x;
  if (i >= ET) return;
  int s, d; edge_sd(src, dst, i, E, s, d);
  atomicAdd(counts + d, 1);
}

// inclusive scan, 1024 elems/block (256 thr x 4). out = rowptr+1.
__global__ __launch_bounds__(256)
void scan_a_kernel(const int* __restrict__ in, int n, int* __restrict__ out,
                   int* __restrict__ bsums) {
  __shared__ int lds[256];
  int t = threadIdx.x;
  int base = blockIdx.x * 1024 + t * 4;
  int v0 = (base + 0 < n) ? in[base + 0] : 0;
  int v1 = (base + 1 < n) ? in[base + 1] : 0;
  int v2 = (base + 2 < n) ? in[base + 2] : 0;
  int v3 = (base + 3 < n) ? in[base + 3] : 0;
  int s1 = v0 + v1, s2 = s1 + v2, s3 = s2 + v3;
  lds[t] = s3;
  __syncthreads();
  for (int o = 1; o < 256; o <<= 1) {
    int x = (t >= o) ? lds[t - o] : 0;
    __syncthreads();
    lds[t] += x;
    __syncthreads();
  }
  int pre = (t > 0) ? lds[t - 1] : 0;
  if (base + 0 < n) out[base + 0] = pre + v0;
  if (base + 1 < n) out[base + 1] = pre + s1;
  if (base + 2 < n) out[base + 2] = pre + s2;
  if (base + 3 < n) out[base + 3] = pre + s3;
  if (t == 255) bsums[blockIdx.x] = lds[255];
}

// single-block inclusive scan of block sums (nb <= 256)
__global__ __launch_bounds__(256)
void scan_b_kernel(int* __restrict__ bs, int nb) {
  __shared__ int lds[256];
  int t = threadIdx.x;
  lds[t] = (t < nb) ? bs[t] : 0;
  __syncthreads();
  for (int o = 1; o < 256; o <<= 1) {
    int x = (t >= o) ? lds[t - o] : 0;
    __syncthreads();
    lds[t] += x;
    __syncthreads();
  }
  if (t < nb) bs[t] = lds[t];
}

__global__ __launch_bounds__(256)
void scan_c_kernel(int* __restrict__ out, int n, const int* __restrict__ bs) {
  int i = blockIdx.x * blockDim.x + threadIdx.x;
  if (i >= n) return;
  int b = i >> 10;
  if (b > 0) out[i] += bs[b - 1];
}

__global__ __launch_bounds__(256)
void fill_kernel(const int* __restrict__ src, const int* __restrict__ dst,
                 int E, int ET, const int* __restrict__ rowptr,
                 int* __restrict__ cursor, int* __restrict__ csr_src) {
  int i = blockIdx.x * blockDim.x + threadIdx.x;
  if (i >= ET) return;
  int s, d; edge_sd(src, dst, i, E, s, d);
  int pos = rowptr[d] + atomicAdd(cursor + d, 1);
  csr_src[pos] = s;
}

// ---------------- dense projection + fused alpha dot-products ----------------
// H[N,OUT_C] = A[N,K] @ W[K,OUT_C]; asN = H.a_src; adN = H.a_dst.
// LDS-pipe diet: A never touches LDS. Each wave loads its 16x20 A-chunk
// global->VGPR as 5 planes (lane l = row l>>2, k-sub l&3; double-buffered
// named regs), and the FMA loop pulls each a-value to an SGPR with
// v_readlane (VALU pipe), feeding v_fmac v,s,v. W (20x200, contiguous 16KB)
// is reg-staged into a single 16.4KB LDS buffer (4 distinct-per-lane b128
// reads per 4k-step — the only LDS traffic). Per 4k-step: LDS 20->4 b128.
__global__ __launch_bounds__(256)
void gemm_ws_kernel(const float* __restrict__ A, const float* __restrict__ W,
                    const float* __restrict__ a_src, const float* __restrict__ a_dst,
                    float* __restrict__ H, float* __restrict__ asN,
                    float* __restrict__ adN, int K, int N) {
  __shared__ float Wf[4096];          // 16.4 KB: flat W chunk [20][200] (+pad)
  int t = threadIdx.x;
  int wave = t >> 6, lane = t & 63;
  int col = lane * 4;                 // 0..252; cols >=200 are garbage lanes
  long row0 = (long)blockIdx.x * BMB;
  int wrow = wave * BMW;

  // ---- W reg-staging: thread t owns f4 slots {t, 256+t, 512+t, 768+t} ----
  const bool pw3ok = t < (WF4 - 768);   // 1000 = 3*256 + 232
  float4 pw0, pw1, pw2, pw3;
  const float* wsrc = W;                // advances 4000 floats per chunk
  auto loadW = [&]() {
    pw0 = *(const float4*)(wsrc + t * 4);
    pw1 = *(const float4*)(wsrc + 1024 + t * 4);
    pw2 = *(const float4*)(wsrc + 2048 + t * 4);
    if (pw3ok) pw3 = *(const float4*)(wsrc + 3072 + t * 4);
    wsrc += BKC * OUT_C;
  };
  auto writeW = [&]() {
    float4* wf4 = (float4*)Wf;
    wf4[t] = pw0; wf4[256 + t] = pw1; wf4[512 + t] = pw2;
    if (pw3ok) wf4[768 + t] = pw3;
  };

  // ---- A planes: direct global->VGPR, no LDS ----
  long arow = row0 + wrow + (lane >> 2);
  if (arow >= N) arow = N - 1;          // clamp (last block), stores masked
  const float* abase = A + arow * K + (lane & 3);
  float plA[5], plB[5];                 // named double buffers (static idx only)
  auto loadA = [&](float (&pl)[5]) {
    #pragma unroll
    for (int p = 0; p < 5; ++p) pl[p] = abase[p * 4];
    abase += BKC;
  };

  float4 acc[BMW];
  #pragma unroll
  for (int r = 0; r < BMW; ++r) acc[r] = make_float4(0.f, 0.f, 0.f, 0.f);

  auto compute = [&](const float (&pl)[5]) {
    #pragma unroll
    for (int p = 0; p < 5; ++p) {
      float4 w0 = *(float4*)&Wf[(p * 4 + 0) * OUT_C + col];
      float4 w1 = *(float4*)&Wf[(p * 4 + 1) * OUT_C + col];
      float4 w2 = *(float4*)&Wf[(p * 4 + 2) * OUT_C + col];
      float4 w3 = *(float4*)&Wf[(p * 4 + 3) * OUT_C + col];
      #pragma unroll
      for (int r = 0; r < BMW; ++r) {
        float a0 = rdlane(pl[p], r * 4 + 0);   // SGPR broadcasts (VALU pipe)
        float a1 = rdlane(pl[p], r * 4 + 1);
        float a2 = rdlane(pl[p], r * 4 + 2);
        float a3 = rdlane(pl[p], r * 4 + 3);
        acc[r].x = fmaf(a0, w0.x, acc[r].x);
        acc[r].x = fmaf(a1, w1.x, acc[r].x);
        acc[r].x = fmaf(a2, w2.x, acc[r].x);
        acc[r].x = fmaf(a3, w3.x, acc[r].x);
        acc[r].y = fmaf(a0, w0.y, acc[r].y);
        acc[r].y = fmaf(a1, w1.y, acc[r].y);
        acc[r].y = fmaf(a2, w2.y, acc[r].y);
        acc[r].y = fmaf(a3, w3.y, acc[r].y);
        acc[r].z = fmaf(a0, w0.z, acc[r].z);
        acc[r].z = fmaf(a1, w1.z, acc[r].z);
        acc[r].z = fmaf(a2, w2.z, acc[r].z);
        acc[r].z = fmaf(a3, w3.z, acc[r].z);
        acc[r].w = fmaf(a0, w0.w, acc[r].w);
        acc[r].w = fmaf(a1, w1.w, acc[r].w);
        acc[r].w = fmaf(a2, w2.w, acc[r].w);
        acc[r].w = fmaf(a3, w3.w, acc[r].w);
      }
    }
  };

  const int nch = K / BKC;
  loadW();
  loadA(plA);
  for (int ch = 0; ch < nch; ch += 2) {
    // even chunk: consume plA, prefetch plB
    __syncthreads();                    // waves done with Wf; pw/planes landed
    writeW();                           // vmcnt already 0: no wait
    __syncthreads();                    // Wf visible (lgkm drain only)
    if (ch + 1 < nch) { loadW(); loadA(plB); }  // fly under the FMAs
    compute(plA);
    if (ch + 1 >= nch) break;
    // odd chunk: consume plB, prefetch plA
    __syncthreads();
    writeW();
    __syncthreads();
    if (ch + 2 < nch) { loadW(); loadA(plA); }
    compute(plB);
  }

  // epilogue: H rows + fused alpha dot-products
  bool cok = col < OUT_C;
  #pragma unroll
  for (int r = 0; r < BMW; ++r) {
    long grow = row0 + wrow + r;
    if (cok && grow < N) *(float4*)(H + grow * OUT_C + col) = acc[r];
  }
  float4 vs = make_float4(0.f, 0.f, 0.f, 0.f);
  float4 vd = make_float4(0.f, 0.f, 0.f, 0.f);
  if (cok) {
    vs = *(const float4*)(a_src + col);
    vd = *(const float4*)(a_dst + col);
  }
  #pragma unroll
  for (int r = 0; r < BMW; ++r) {
    float ss = acc[r].x * vs.x + acc[r].y * vs.y + acc[r].z * vs.z + acc[r].w * vs.w;
    float sd = acc[r].x * vd.x + acc[r].y * vd.y + acc[r].z * vd.z + acc[r].w * vd.w;
    #pragma unroll
    for (int o = 32; o > 0; o >>= 1) {
      ss += __shfl_xor(ss, o);
      sd += __shfl_xor(sd, o);
    }
    long grow = row0 + wrow + r;
    if (lane == 0 && grow < N) { asN[grow] = ss; adN[grow] = sd; }
  }
}

// ---------------- fused segment-softmax + gather-aggregate + bias + relu ----
// One wave per destination node. Single edge walk (softmax without max-sub;
// scores O(+-10), fp32-safe). se accumulated redundantly per-lane. Edge walk
// unrolled x4: 16 float4 row-loads in flight (latency-bound loop).
__global__ __launch_bounds__(256)
void gather_agg_kernel(const float* __restrict__ h, const float* __restrict__ asN,
                       const float* __restrict__ adN, const int* __restrict__ rowptr,
                       const int* __restrict__ csr_src, const float* __restrict__ bias,
                       float* __restrict__ out, int N) {
  int wid = (int)(((long)blockIdx.x * blockDim.x + threadIdx.x) >> 6);
  int lane = threadIdx.x & 63;
  if (wid >= N) return;
  int start = rowptr[wid], end = rowptr[wid + 1];
  float ad = adN[wid];
  int c = lane * 4;
  bool cok = c < OUT_C;
  const float* hc = h + c;

  float4 acc = make_float4(0.f, 0.f, 0.f, 0.f);
  float se = 0.f;
  int j = start;
  for (; j + 4 <= end; j += 4) {
    int s0 = csr_src[j], s1 = csr_src[j + 1];
    int s2 = csr_src[j + 2], s3 = csr_src[j + 3];
    float e0 = asN[s0] + ad, e1 = asN[s1] + ad;
    float e2 = asN[s2] + ad, e3 = asN[s3] + ad;
    e0 = e0 > 0.f ? e0 : NEG_SLOPE * e0;
    e1 = e1 > 0.f ? e1 : NEG_SLOPE * e1;
    e2 = e2 > 0.f ? e2 : NEG_SLOPE * e2;
    e3 = e3 > 0.f ? e3 : NEG_SLOPE * e3;
    float w0 = __expf(e0), w1 = __expf(e1), w2 = __expf(e2), w3 = __expf(e3);
    se += (w0 + w1) + (w2 + w3);
    if (cok) {
      float4 h0 = *(const float4*)(hc + (long)s0 * OUT_C);
      float4 h1 = *(const float4*)(hc + (long)s1 * OUT_C);
      float4 h2 = *(const float4*)(hc + (long)s2 * OUT_C);
      float4 h3 = *(const float4*)(hc + (long)s3 * OUT_C);
      acc.x = fmaf(w0, h0.x, acc.x); acc.x = fmaf(w1, h1.x, acc.x);
      acc.x = fmaf(w2, h2.x, acc.x); acc.x = fmaf(w3, h3.x, acc.x);
      acc.y = fmaf(w0, h0.y, acc.y); acc.y = fmaf(w1, h1.y, acc.y);
      acc.y = fmaf(w2, h2.y, acc.y); acc.y = fmaf(w3, h3.y, acc.y);
      acc.z = fmaf(w0, h0.z, acc.z); acc.z = fmaf(w1, h1.z, acc.z);
      acc.z = fmaf(w2, h2.z, acc.z); acc.z = fmaf(w3, h3.z, acc.z);
      acc.w = fmaf(w0, h0.w, acc.w); acc.w = fmaf(w1, h1.w, acc.w);
      acc.w = fmaf(w2, h2.w, acc.w); acc.w = fmaf(w3, h3.w, acc.w);
    }
  }
  for (; j < end; ++j) {
    int s0 = csr_src[j];
    float e0 = asN[s0] + ad;
    e0 = e0 > 0.f ? e0 : NEG_SLOPE * e0;
    float w0 = __expf(e0);
    se += w0;
    if (cok) {
      float4 h0 = *(const float4*)(hc + (long)s0 * OUT_C);
      acc.x = fmaf(w0, h0.x, acc.x);
      acc.y = fmaf(w0, h0.y, acc.y);
      acc.z = fmaf(w0, h0.z, acc.z);
      acc.w = fmaf(w0, h0.w, acc.w);
    }
  }
  if (cok) {
    float inv = 1.0f / se;
    float4 bv = *(const float4*)(bias + c);
    float4 o;
    o.x = fmaxf(fmaf(acc.x, inv, bv.x), 0.f);
    o.y = fmaxf(fmaf(acc.y, inv, bv.y), 0.f);
    o.z = fmaxf(fmaf(acc.z, inv, bv.z), 0.f);
    o.w = fmaxf(fmaf(acc.w, inv, bv.w), 0.f);
    *(float4*)(out + (long)wid * OUT_C + c) = o;
  }
}

// ---------------- driver ----------------
static void run_layer(const float* xin, int K, const float* W,
                      const float* a_s, const float* a_d, const float* b,
                      const int* rowptr, const int* csr_src, int N,
                      float* hbuf, float* asN, float* adN, float* outbuf,
                      hipStream_t stream) {
  gemm_ws_kernel<<<cdiv(N, BMB), 256, 0, stream>>>(xin, W, a_s, a_d,
                                                   hbuf, asN, adN, K, N);
  gather_agg_kernel<<<cdiv((long)N * 64, 256), 256, 0, stream>>>(
      hbuf, asN, adN, rowptr, csr_src, b, outbuf, N);
}

extern "C" void kernel_launch(void* const* d_in, const int* in_sizes, int n_in,
                              void* d_out, int out_size, void* d_ws, size_t ws_size,
                              hipStream_t stream) {
  const float* x   = (const float*)d_in[0];
  const float* W0  = (const float*)d_in[1];
  const float* as0 = (const float*)d_in[2];
  const float* ad0 = (const float*)d_in[3];
  const float* b0  = (const float*)d_in[4];
  const float* W1  = (const float*)d_in[5];
  const float* as1 = (const float*)d_in[6];
  const float* ad1 = (const float*)d_in[7];
  const float* b1  = (const float*)d_in[8];
  const int*   ei  = (const int*)d_in[9];

  const int N  = in_sizes[0] / IN_C;
  const int E  = in_sizes[9] / 2;
  const int ET = E + N;
  const int* src = ei;
  const int* dst = ei + E;

  float* out = (float*)d_out;

  char* ws = (char*)d_ws;
  float* hbuf   = (float*)ws;                                  // N*OUT_C
  float* asN    = (float*)(ws + (size_t)N * OUT_C * 4);        // N
  float* adN    = asN + N;                                     // N
  int*   rowptr = (int*)(adN + N);                             // N+1
  int*   counts = rowptr + (N + 1);                            // N (also cursor)
  int*   bsums  = counts + N;                                  // 256
  int*   csrsrc = bsums + 256;                                 // ET

  const int nb = cdiv(N, 1024);

  // ---- one-time CSR build (shared by both layers) ----
  zero_int_kernel<<<cdiv(N, 256), 256, 0, stream>>>(counts, N);
  hist_kernel<<<cdiv(ET, 256), 256, 0, stream>>>(src, dst, E, ET, counts);
  scan_a_kernel<<<nb, 256, 0, stream>>>(counts, N, rowptr + 1, bsums);
  scan_b_kernel<<<1, 256, 0, stream>>>(bsums, nb);
  scan_c_kernel<<<cdiv(N, 256), 256, 0, stream>>>(rowptr + 1, N, bsums);
  zero_int_kernel<<<1, 256, 0, stream>>>(rowptr, 1);
  zero_int_kernel<<<cdiv(N, 256), 256, 0, stream>>>(counts, N);  // reuse as cursor
  fill_kernel<<<cdiv(ET, 256), 256, 0, stream>>>(src, dst, E, ET, rowptr, counts, csrsrc);

  // ---- layer 0: x -> out ----
  run_layer(x, IN_C, W0, as0, ad0, b0, rowptr, csrsrc, N, hbuf, asN, adN, out, stream);
  // ---- layer 1: out -> out (gemm reads out before gather_agg rewrites it) ----
  run_layer(out, OUT_C, W1, as1, ad1, b1, rowptr, csrsrc, N, hbuf, asN, adN, out, stream);
}